// Round 1
// baseline (353.494 us; speedup 1.0000x reference)
//
#include <hip/hip_runtime.h>
#include <hip/hip_bf16.h>
#include <stdint.h>

static constexpr int M = 4096, N = 4096, K = 4096;
static constexpr float FP8_MAX = 448.0f;

using f32x4 = __attribute__((ext_vector_type(4))) float;
using i64 = long;

// ---------------- ws layout ----------------
// [0, 16MB)         : Aq fp8  [M][K] row-major  (quantized x)
// [16MB, 32MB)      : Bq fp8  [N][K] row-major  (quantized weight, natural layout == B^T)
// [32MB, 32MB+8)    : amax_x, amax_w (float)
static constexpr size_t AQ_OFF   = 0;
static constexpr size_t BQ_OFF   = (size_t)M * K;
static constexpr size_t AMAX_OFF = BQ_OFF + (size_t)N * K;

// ---------------- init ----------------
__global__ void init_amax_kernel(float* amax) {
    amax[0] = 0.0f;
    amax[1] = 0.0f;
}

// ---------------- amax reduction ----------------
__global__ __launch_bounds__(256) void amax_kernel(const float* __restrict__ x,
                                                   const float* __restrict__ w,
                                                   float* __restrict__ amax,
                                                   int n4_per_tensor,
                                                   int blocks_per_tensor) {
    const int tensor = blockIdx.x / blocks_per_tensor;
    const int blk    = blockIdx.x % blocks_per_tensor;
    const float4* src = (const float4*)(tensor == 0 ? x : w);

    float m = 0.0f;
    for (int i = blk * blockDim.x + threadIdx.x; i < n4_per_tensor;
         i += blocks_per_tensor * blockDim.x) {
        float4 v = src[i];
        m = fmaxf(m, fmaxf(fmaxf(fabsf(v.x), fabsf(v.y)),
                           fmaxf(fabsf(v.z), fabsf(v.w))));
    }
    // wave64 butterfly reduce
    #pragma unroll
    for (int off = 32; off >= 1; off >>= 1)
        m = fmaxf(m, __shfl_xor(m, off, 64));

    __shared__ float sm[4];
    const int lane = threadIdx.x & 63, wid = threadIdx.x >> 6;
    if (lane == 0) sm[wid] = m;
    __syncthreads();
    if (threadIdx.x == 0) {
        m = fmaxf(fmaxf(sm[0], sm[1]), fmaxf(sm[2], sm[3]));
        atomicMax((unsigned int*)&amax[tensor], __float_as_uint(m));
    }
}

// ---------------- quantize to fp8 e4m3fn ----------------
__global__ __launch_bounds__(256) void quant_kernel(const float* __restrict__ x,
                                                    const float* __restrict__ w,
                                                    unsigned char* __restrict__ aq,
                                                    unsigned char* __restrict__ bq,
                                                    const float* __restrict__ amax,
                                                    int n4_per_tensor) {
    int gid = blockIdx.x * blockDim.x + threadIdx.x;
    const int tensor = (gid >= n4_per_tensor) ? 1 : 0;
    const int i = tensor ? gid - n4_per_tensor : gid;

    const float inv = fmaxf(amax[tensor], 1e-12f) / FP8_MAX;
    const float4* src = (const float4*)(tensor == 0 ? x : w);
    int* dst = (int*)(tensor == 0 ? aq : bq);

    float4 v = src[i];
    // IEEE division to bitwise-match the reference's x / inv_scale
    float q0 = v.x / inv, q1 = v.y / inv, q2 = v.z / inv, q3 = v.w / inv;
    int packed = __builtin_amdgcn_cvt_pk_fp8_f32(q0, q1, 0, false);
    packed     = __builtin_amdgcn_cvt_pk_fp8_f32(q2, q3, packed, true);
    dst[i] = packed;
}

// ---------------- fp8 GEMM, m97 structure ----------------
// C[m][n] = sum_k Aq[m][k]*Bq[n][k];  out = C*scale + bias[n]
static constexpr int BM = 128, BN = 128, BK = 64;

__device__ __forceinline__ void gld_lds16(const void* g, void* l) {
    __builtin_amdgcn_global_load_lds(
        (const __attribute__((address_space(1))) void*)g,
        (__attribute__((address_space(3))) void*)l, 16, 0, 0);
}

__global__ __launch_bounds__(256) void gemm_kernel(const unsigned char* __restrict__ Aq,
                                                   const unsigned char* __restrict__ Bq,
                                                   const float* __restrict__ amax,
                                                   const float* __restrict__ bias,
                                                   float* __restrict__ out) {
    __shared__ unsigned char Alds[BM * BK];  // 8 KB, [128][64] linear
    __shared__ unsigned char Blds[BN * BK];  // 8 KB

    const int tid  = threadIdx.x;
    const int lane = tid & 63;
    const int wid  = tid >> 6;
    const int brow = blockIdx.y * BM;
    const int bcol = blockIdx.x * BN;
    const int wr = wid >> 1, wc = wid & 1;   // 2x2 waves, each owns 64x64

    const float sx = fmaxf(amax[0], 1e-12f) / FP8_MAX;
    const float sw = fmaxf(amax[1], 1e-12f) / FP8_MAX;
    const float scale = sx * sw;

    f32x4 acc[4][4] = {};

    const int seg0 = wid * 2, seg1 = wid * 2 + 1;
    const int srow = lane >> 2;            // row within 16-row segment
    const int scol = (lane & 3) * 16;      // byte col within 64B row
    const unsigned char* Abase = Aq + (size_t)brow * K;
    const unsigned char* Bbase = Bq + (size_t)bcol * K;

    for (int k0 = 0; k0 < K; k0 += BK) {
        // stage global -> LDS (linear dest, wave-uniform base + lane*16)
        gld_lds16(Abase + (size_t)(seg0 * 16 + srow) * K + k0 + scol, &Alds[seg0 * 1024]);
        gld_lds16(Abase + (size_t)(seg1 * 16 + srow) * K + k0 + scol, &Alds[seg1 * 1024]);
        gld_lds16(Bbase + (size_t)(seg0 * 16 + srow) * K + k0 + scol, &Blds[seg0 * 1024]);
        gld_lds16(Bbase + (size_t)(seg1 * 16 + srow) * K + k0 + scol, &Blds[seg1 * 1024]);
        __syncthreads();   // drains vmcnt (global_load_lds) + lgkmcnt

        #pragma unroll
        for (int ks = 0; ks < 2; ++ks) {
            i64 aF[4], bF[4];
            #pragma unroll
            for (int m = 0; m < 4; ++m)
                aF[m] = *(const i64*)&Alds[(wr * 64 + m * 16 + (lane & 15)) * BK + ks * 32 + (lane >> 4) * 8];
            #pragma unroll
            for (int n = 0; n < 4; ++n)
                bF[n] = *(const i64*)&Blds[(wc * 64 + n * 16 + (lane & 15)) * BK + ks * 32 + (lane >> 4) * 8];
            #pragma unroll
            for (int m = 0; m < 4; ++m)
                #pragma unroll
                for (int n = 0; n < 4; ++n)
                    acc[m][n] = __builtin_amdgcn_mfma_f32_16x16x32_fp8_fp8(
                        aF[m], bF[n], acc[m][n], 0, 0, 0);
        }
        __syncthreads();
    }

    // epilogue: out = acc*scale + bias.  C/D layout: col=lane&15, row=(lane>>4)*4+j
    #pragma unroll
    for (int m = 0; m < 4; ++m) {
        const int row0 = brow + wr * 64 + m * 16 + (lane >> 4) * 4;
        #pragma unroll
        for (int n = 0; n < 4; ++n) {
            const int col = bcol + wc * 64 + n * 16 + (lane & 15);
            const float b = bias[col];
            #pragma unroll
            for (int j = 0; j < 4; ++j)
                out[(size_t)(row0 + j) * N + col] = acc[m][n][j] * scale + b;
        }
    }
}

extern "C" void kernel_launch(void* const* d_in, const int* in_sizes, int n_in,
                              void* d_out, int out_size, void* d_ws, size_t ws_size,
                              hipStream_t stream) {
    const float* x    = (const float*)d_in[0];   // [4,1024,4096] f32 -> [4096][4096]
    const float* w    = (const float*)d_in[1];   // [4096][4096] f32
    const float* bias = (const float*)d_in[2];   // [4096] f32
    float* out = (float*)d_out;

    unsigned char* aq = (unsigned char*)d_ws + AQ_OFF;
    unsigned char* bq = (unsigned char*)d_ws + BQ_OFF;
    float* amax = (float*)((unsigned char*)d_ws + AMAX_OFF);

    const int n4 = (M * K) / 4;                  // 4,194,304 float4 per tensor

    init_amax_kernel<<<1, 1, 0, stream>>>(amax);

    const int blocks_per_tensor = 512;
    amax_kernel<<<2 * blocks_per_tensor, 256, 0, stream>>>(x, w, amax, n4, blocks_per_tensor);

    const int quant_blocks = (2 * n4) / 256;     // 32768 blocks, 1 float4/thread
    quant_kernel<<<quant_blocks, 256, 0, stream>>>(x, w, aq, bq, amax, n4);

    dim3 grid(N / BN, M / BM);                   // (32, 32)
    gemm_kernel<<<grid, 256, 0, stream>>>(aq, bq, amax, bias, out);
}

// Round 2
// 181.800 us; speedup vs baseline: 1.9444x; 1.9444x over previous
//
#include <hip/hip_runtime.h>
#include <hip/hip_bf16.h>
#include <stdint.h>

static constexpr int M = 4096, N = 4096, K = 4096;
static constexpr float FP8_MAX = 448.0f;

using f32x4 = __attribute__((ext_vector_type(4))) float;
using i64 = long;

// ---------------- ws layout ----------------
// [0, 16MB)         : Aq fp8  [M][K] row-major  (quantized x)
// [16MB, 32MB)      : Bq fp8  [N][K] row-major  (quantized weight, natural layout == B^T)
// [32MB, 32MB+8)    : amax_x, amax_w (float)
static constexpr size_t AQ_OFF   = 0;
static constexpr size_t BQ_OFF   = (size_t)M * K;
static constexpr size_t AMAX_OFF = BQ_OFF + (size_t)N * K;

// ---------------- init ----------------
__global__ void init_amax_kernel(float* amax) {
    amax[0] = 0.0f;
    amax[1] = 0.0f;
}

// ---------------- amax reduction ----------------
__global__ __launch_bounds__(256) void amax_kernel(const float* __restrict__ x,
                                                   const float* __restrict__ w,
                                                   float* __restrict__ amax,
                                                   int n4_per_tensor,
                                                   int blocks_per_tensor) {
    const int tensor = blockIdx.x / blocks_per_tensor;
    const int blk    = blockIdx.x % blocks_per_tensor;
    const float4* src = (const float4*)(tensor == 0 ? x : w);

    float m = 0.0f;
    for (int i = blk * blockDim.x + threadIdx.x; i < n4_per_tensor;
         i += blocks_per_tensor * blockDim.x) {
        float4 v = src[i];
        m = fmaxf(m, fmaxf(fmaxf(fabsf(v.x), fabsf(v.y)),
                           fmaxf(fabsf(v.z), fabsf(v.w))));
    }
    // wave64 butterfly reduce
    #pragma unroll
    for (int off = 32; off >= 1; off >>= 1)
        m = fmaxf(m, __shfl_xor(m, off, 64));

    __shared__ float sm[4];
    const int lane = threadIdx.x & 63, wid = threadIdx.x >> 6;
    if (lane == 0) sm[wid] = m;
    __syncthreads();
    if (threadIdx.x == 0) {
        m = fmaxf(fmaxf(sm[0], sm[1]), fmaxf(sm[2], sm[3]));
        atomicMax((unsigned int*)&amax[tensor], __float_as_uint(m));
    }
}

// ---------------- quantize to fp8 e4m3fn ----------------
__global__ __launch_bounds__(256) void quant_kernel(const float* __restrict__ x,
                                                    const float* __restrict__ w,
                                                    unsigned char* __restrict__ aq,
                                                    unsigned char* __restrict__ bq,
                                                    const float* __restrict__ amax,
                                                    int n4_per_tensor) {
    int gid = blockIdx.x * blockDim.x + threadIdx.x;
    const int tensor = (gid >= n4_per_tensor) ? 1 : 0;
    const int i = tensor ? gid - n4_per_tensor : gid;

    const float inv = fmaxf(amax[tensor], 1e-12f) / FP8_MAX;
    const float4* src = (const float4*)(tensor == 0 ? x : w);
    int* dst = (int*)(tensor == 0 ? aq : bq);

    float4 v = src[i];
    // IEEE division to bitwise-match the reference's x / inv_scale
    float q0 = v.x / inv, q1 = v.y / inv, q2 = v.z / inv, q3 = v.w / inv;
    int packed = __builtin_amdgcn_cvt_pk_fp8_f32(q0, q1, 0, false);
    packed     = __builtin_amdgcn_cvt_pk_fp8_f32(q2, q3, packed, true);
    dst[i] = packed;
}

// ---------------- fp8 GEMM, m97 structure + chunk-XOR LDS swizzle ----------------
// C[m][n] = sum_k Aq[m][k]*Bq[n][k];  out = C*scale + bias[n]
//
// LDS physical layout: lds[row][chunk ^ swz(row)] holds global chunk, where
// chunks are 16B units of the 64B row and swz(row) = (row>>1)&3.
// Bank math for a fragment read group (16 lanes = 16 rows, fixed col):
//   bank = 16*(row&1) + 4*(chunk ^ swz(row)) + dword-in-chunk
// -> all 8 (row&1, chunk)-combos covered twice -> 2 lanes/bank (free, m136).
// global_load_lds writes linearly (lane*16), so the swizzle is applied by
// PRE-SWIZZLING the global source chunk (rule #21 / m173 pattern).
static constexpr int BM = 128, BN = 128, BK = 64;

__device__ __forceinline__ void gld_lds16(const void* g, void* l) {
    __builtin_amdgcn_global_load_lds(
        (const __attribute__((address_space(1))) void*)g,
        (__attribute__((address_space(3))) void*)l, 16, 0, 0);
}

__global__ __launch_bounds__(256) void gemm_kernel(const unsigned char* __restrict__ Aq,
                                                   const unsigned char* __restrict__ Bq,
                                                   const float* __restrict__ amax,
                                                   const float* __restrict__ bias,
                                                   float* __restrict__ out) {
    __shared__ unsigned char Alds[BM * BK];  // 8 KB
    __shared__ unsigned char Blds[BN * BK];  // 8 KB

    const int tid  = threadIdx.x;
    const int lane = tid & 63;
    const int wid  = tid >> 6;
    const int brow = blockIdx.y * BM;
    const int bcol = blockIdx.x * BN;
    const int wr = wid >> 1, wc = wid & 1;   // 2x2 waves, each owns 64x64

    const float sx = fmaxf(amax[0], 1e-12f) / FP8_MAX;
    const float sw = fmaxf(amax[1], 1e-12f) / FP8_MAX;
    const float scale = sx * sw;

    f32x4 acc[4][4] = {};

    // ---- staging addresses (pre-swizzled global source, linear LDS dest) ----
    const int seg0 = wid * 2, seg1 = wid * 2 + 1;
    const int srow  = lane >> 2;                       // row within 16-row segment
    const int swz_s = (srow >> 1) & 3;                 // swizzle for that row
    const int scol  = ((lane & 3) ^ swz_s) * 16;       // swizzled global chunk
    const unsigned char* Abase = Aq + (size_t)brow * K;
    const unsigned char* Bbase = Bq + (size_t)bcol * K;

    // ---- fragment read addresses (swizzled LDS) ----
    const int rl = lane & 15;          // row-in-16 for fragment reads
    const int hi = lane >> 4;          // 0..3 -> k sub-slot
    const int swzr = (rl >> 1) & 3;
    // logical col for ks: c = ks*32 + hi*8; chunk = ks*2 + (hi>>1); byte = (hi&1)*8
    int col_swz[2];
    #pragma unroll
    for (int ks = 0; ks < 2; ++ks)
        col_swz[ks] = (((ks * 2 + (hi >> 1)) ^ swzr) << 4) + (hi & 1) * 8;

    for (int k0 = 0; k0 < K; k0 += BK) {
        gld_lds16(Abase + (size_t)(seg0 * 16 + srow) * K + k0 + scol, &Alds[seg0 * 1024]);
        gld_lds16(Abase + (size_t)(seg1 * 16 + srow) * K + k0 + scol, &Alds[seg1 * 1024]);
        gld_lds16(Bbase + (size_t)(seg0 * 16 + srow) * K + k0 + scol, &Blds[seg0 * 1024]);
        gld_lds16(Bbase + (size_t)(seg1 * 16 + srow) * K + k0 + scol, &Blds[seg1 * 1024]);
        __syncthreads();   // drains vmcnt (global_load_lds) + lgkmcnt

        #pragma unroll
        for (int ks = 0; ks < 2; ++ks) {
            i64 aF[4], bF[4];
            #pragma unroll
            for (int m = 0; m < 4; ++m)
                aF[m] = *(const i64*)&Alds[(wr * 64 + m * 16 + rl) * BK + col_swz[ks]];
            #pragma unroll
            for (int n = 0; n < 4; ++n)
                bF[n] = *(const i64*)&Blds[(wc * 64 + n * 16 + rl) * BK + col_swz[ks]];
            #pragma unroll
            for (int m = 0; m < 4; ++m)
                #pragma unroll
                for (int n = 0; n < 4; ++n)
                    acc[m][n] = __builtin_amdgcn_mfma_f32_16x16x32_fp8_fp8(
                        aF[m], bF[n], acc[m][n], 0, 0, 0);
        }
        __syncthreads();
    }

    // epilogue: out = acc*scale + bias.  C/D layout: col=lane&15, row=(lane>>4)*4+j
    #pragma unroll
    for (int m = 0; m < 4; ++m) {
        const int row0 = brow + wr * 64 + m * 16 + (lane >> 4) * 4;
        #pragma unroll
        for (int n = 0; n < 4; ++n) {
            const int col = bcol + wc * 64 + n * 16 + (lane & 15);
            const float b = bias[col];
            #pragma unroll
            for (int j = 0; j < 4; ++j)
                out[(size_t)(row0 + j) * N + col] = acc[m][n][j] * scale + b;
        }
    }
}

extern "C" void kernel_launch(void* const* d_in, const int* in_sizes, int n_in,
                              void* d_out, int out_size, void* d_ws, size_t ws_size,
                              hipStream_t stream) {
    const float* x    = (const float*)d_in[0];   // [4,1024,4096] f32 -> [4096][4096]
    const float* w    = (const float*)d_in[1];   // [4096][4096] f32
    const float* bias = (const float*)d_in[2];   // [4096] f32
    float* out = (float*)d_out;

    unsigned char* aq = (unsigned char*)d_ws + AQ_OFF;
    unsigned char* bq = (unsigned char*)d_ws + BQ_OFF;
    float* amax = (float*)((unsigned char*)d_ws + AMAX_OFF);

    const int n4 = (M * K) / 4;                  // 4,194,304 float4 per tensor

    init_amax_kernel<<<1, 1, 0, stream>>>(amax);

    const int blocks_per_tensor = 512;
    amax_kernel<<<2 * blocks_per_tensor, 256, 0, stream>>>(x, w, amax, n4, blocks_per_tensor);

    const int quant_blocks = (2 * n4) / 256;     // 32768 blocks, 1 float4/thread
    quant_kernel<<<quant_blocks, 256, 0, stream>>>(x, w, aq, bq, amax, n4);

    dim3 grid(N / BN, M / BM);                   // (32, 32)
    gemm_kernel<<<grid, 256, 0, stream>>>(aq, bq, amax, bias, out);
}

// Round 3
// 157.727 us; speedup vs baseline: 2.2412x; 1.1526x over previous
//
#include <hip/hip_runtime.h>
#include <hip/hip_bf16.h>
#include <stdint.h>

static constexpr int M = 4096, N = 4096, K = 4096;
static constexpr float FP8_MAX = 448.0f;

using f32x4  = __attribute__((ext_vector_type(4))) float;
using f32x16 = __attribute__((ext_vector_type(16))) float;
using i32x4  = __attribute__((ext_vector_type(4))) int;
using i32x8  = __attribute__((ext_vector_type(8))) int;

// ---------------- ws layout ----------------
// [0, 16MB)         : Aq fp8  [M][K] row-major  (quantized x)
// [16MB, 32MB)      : Bq fp8  [N][K] row-major  (quantized weight, natural layout == B^T)
// [32MB, 32MB+8)    : amax_x, amax_w (float)
static constexpr size_t AQ_OFF   = 0;
static constexpr size_t BQ_OFF   = (size_t)M * K;
static constexpr size_t AMAX_OFF = BQ_OFF + (size_t)N * K;

// ---------------- init ----------------
__global__ void init_amax_kernel(float* amax) {
    amax[0] = 0.0f;
    amax[1] = 0.0f;
}

// ---------------- amax reduction ----------------
__global__ __launch_bounds__(256) void amax_kernel(const float* __restrict__ x,
                                                   const float* __restrict__ w,
                                                   float* __restrict__ amax,
                                                   int n4_per_tensor,
                                                   int blocks_per_tensor) {
    const int tensor = blockIdx.x / blocks_per_tensor;
    const int blk    = blockIdx.x % blocks_per_tensor;
    const float4* src = (const float4*)(tensor == 0 ? x : w);

    float m = 0.0f;
    for (int i = blk * blockDim.x + threadIdx.x; i < n4_per_tensor;
         i += blocks_per_tensor * blockDim.x) {
        float4 v = src[i];
        m = fmaxf(m, fmaxf(fmaxf(fabsf(v.x), fabsf(v.y)),
                           fmaxf(fabsf(v.z), fabsf(v.w))));
    }
    #pragma unroll
    for (int off = 32; off >= 1; off >>= 1)
        m = fmaxf(m, __shfl_xor(m, off, 64));

    __shared__ float sm[4];
    const int lane = threadIdx.x & 63, wid = threadIdx.x >> 6;
    if (lane == 0) sm[wid] = m;
    __syncthreads();
    if (threadIdx.x == 0) {
        m = fmaxf(fmaxf(sm[0], sm[1]), fmaxf(sm[2], sm[3]));
        atomicMax((unsigned int*)&amax[tensor], __float_as_uint(m));
    }
}

// ---------------- quantize to fp8 e4m3fn ----------------
__global__ __launch_bounds__(256) void quant_kernel(const float* __restrict__ x,
                                                    const float* __restrict__ w,
                                                    unsigned char* __restrict__ aq,
                                                    unsigned char* __restrict__ bq,
                                                    const float* __restrict__ amax,
                                                    int n4_per_tensor) {
    int gid = blockIdx.x * blockDim.x + threadIdx.x;
    const int tensor = (gid >= n4_per_tensor) ? 1 : 0;
    const int i = tensor ? gid - n4_per_tensor : gid;

    const float inv = fmaxf(amax[tensor], 1e-12f) / FP8_MAX;
    const float4* src = (const float4*)(tensor == 0 ? x : w);
    int* dst = (int*)(tensor == 0 ? aq : bq);

    float4 v = src[i];
    float q0 = v.x / inv, q1 = v.y / inv, q2 = v.z / inv, q3 = v.w / inv;
    int packed = __builtin_amdgcn_cvt_pk_fp8_f32(q0, q1, 0, false);
    packed     = __builtin_amdgcn_cvt_pk_fp8_f32(q2, q3, packed, true);
    dst[i] = packed;
}

// ---------------- fp8 GEMM: m97 structure + chunk-XOR swizzle + MX 32x32x64 ----
// C[m][n] = sum_k Aq[m][k]*Bq[n][k];  out = C*scale + bias[n]
// MX-scaled mfma with UNIT scales (E8M0 0x7F = 2^0) -> math identical to
// non-scaled fp8, but at the 2x f8f6f4 rate (m148 ladder step).
static constexpr int BM = 128, BN = 128, BK = 64;

__device__ __forceinline__ void gld_lds16(const void* g, void* l) {
    __builtin_amdgcn_global_load_lds(
        (const __attribute__((address_space(1))) void*)g,
        (__attribute__((address_space(3))) void*)l, 16, 0, 0);
}

__global__ __launch_bounds__(256) void gemm_kernel(const unsigned char* __restrict__ Aq,
                                                   const unsigned char* __restrict__ Bq,
                                                   const float* __restrict__ amax,
                                                   const float* __restrict__ bias,
                                                   float* __restrict__ out) {
    __shared__ unsigned char Alds[BM * BK];  // 8 KB
    __shared__ unsigned char Blds[BN * BK];  // 8 KB

    const int tid  = threadIdx.x;
    const int lane = tid & 63;
    const int wid  = tid >> 6;
    const int brow = blockIdx.y * BM;
    const int bcol = blockIdx.x * BN;
    const int wr = wid >> 1, wc = wid & 1;   // 2x2 waves, each owns 64x64

    const float sx = fmaxf(amax[0], 1e-12f) / FP8_MAX;
    const float sw = fmaxf(amax[1], 1e-12f) / FP8_MAX;
    const float scale = sx * sw;

    f32x16 acc[2][2] = {};

    // ---- staging addresses (pre-swizzled global source, linear LDS dest) ----
    const int seg0 = wid * 2, seg1 = wid * 2 + 1;
    const int srow  = lane >> 2;                       // row within 16-row segment
    const int swz_s = (srow >> 1) & 3;
    const int scol  = ((lane & 3) ^ swz_s) * 16;       // swizzled global chunk
    const unsigned char* Abase = Aq + (size_t)brow * K;
    const unsigned char* Bbase = Bq + (size_t)bcol * K;

    // ---- fragment read addresses (swizzled LDS) ----
    // 32x32x64 A/B layout: row = lane&31, k = (lane>>5)*32 + [0..32)
    const int frow = lane & 31;
    const int c0   = (lane >> 5) * 2;                  // first 16B chunk of the 32B
    const int swzr = (frow >> 1) & 3;
    const int off0 = ((c0 ^ swzr) << 4);
    const int off1 = (((c0 + 1) ^ swzr) << 4);

    for (int k0 = 0; k0 < K; k0 += BK) {
        gld_lds16(Abase + (size_t)(seg0 * 16 + srow) * K + k0 + scol, &Alds[seg0 * 1024]);
        gld_lds16(Abase + (size_t)(seg1 * 16 + srow) * K + k0 + scol, &Alds[seg1 * 1024]);
        gld_lds16(Bbase + (size_t)(seg0 * 16 + srow) * K + k0 + scol, &Blds[seg0 * 1024]);
        gld_lds16(Bbase + (size_t)(seg1 * 16 + srow) * K + k0 + scol, &Blds[seg1 * 1024]);
        __syncthreads();   // drains vmcnt (global_load_lds) + lgkmcnt

        i32x8 aF[2], bF[2];
        #pragma unroll
        for (int m = 0; m < 2; ++m) {
            const unsigned char* p = &Alds[(wr * 64 + m * 32 + frow) * BK];
            i32x4 lo = *(const i32x4*)(p + off0);
            i32x4 hi = *(const i32x4*)(p + off1);
            aF[m] = __builtin_shufflevector(lo, hi, 0, 1, 2, 3, 4, 5, 6, 7);
        }
        #pragma unroll
        for (int n = 0; n < 2; ++n) {
            const unsigned char* p = &Blds[(wc * 64 + n * 32 + frow) * BK];
            i32x4 lo = *(const i32x4*)(p + off0);
            i32x4 hi = *(const i32x4*)(p + off1);
            bF[n] = __builtin_shufflevector(lo, hi, 0, 1, 2, 3, 4, 5, 6, 7);
        }
        #pragma unroll
        for (int m = 0; m < 2; ++m)
            #pragma unroll
            for (int n = 0; n < 2; ++n)
                acc[m][n] = __builtin_amdgcn_mfma_scale_f32_32x32x64_f8f6f4(
                    aF[m], bF[n], acc[m][n],
                    0 /*cbsz: fp8 e4m3*/, 0 /*blgp: fp8 e4m3*/,
                    0, 0x7F /*unit scale A*/, 0, 0x7F /*unit scale B*/);
        __syncthreads();
    }

    // epilogue.  32x32 C/D layout: col=lane&31, row=(reg&3)+8*(reg>>2)+4*(lane>>5)
    #pragma unroll
    for (int m = 0; m < 2; ++m) {
        const int rbase = brow + wr * 64 + m * 32 + 4 * (lane >> 5);
        #pragma unroll
        for (int n = 0; n < 2; ++n) {
            const int col = bcol + wc * 64 + n * 32 + (lane & 31);
            const float b = bias[col];
            #pragma unroll
            for (int reg = 0; reg < 16; ++reg) {
                const int row = rbase + (reg & 3) + 8 * (reg >> 2);
                out[(size_t)row * N + col] = acc[m][n][reg] * scale + b;
            }
        }
    }
}

extern "C" void kernel_launch(void* const* d_in, const int* in_sizes, int n_in,
                              void* d_out, int out_size, void* d_ws, size_t ws_size,
                              hipStream_t stream) {
    const float* x    = (const float*)d_in[0];   // [4,1024,4096] f32 -> [4096][4096]
    const float* w    = (const float*)d_in[1];   // [4096][4096] f32
    const float* bias = (const float*)d_in[2];   // [4096] f32
    float* out = (float*)d_out;

    unsigned char* aq = (unsigned char*)d_ws + AQ_OFF;
    unsigned char* bq = (unsigned char*)d_ws + BQ_OFF;
    float* amax = (float*)((unsigned char*)d_ws + AMAX_OFF);

    const int n4 = (M * K) / 4;                  // 4,194,304 float4 per tensor

    init_amax_kernel<<<1, 1, 0, stream>>>(amax);

    const int blocks_per_tensor = 512;
    amax_kernel<<<2 * blocks_per_tensor, 256, 0, stream>>>(x, w, amax, n4, blocks_per_tensor);

    const int quant_blocks = (2 * n4) / 256;     // 32768 blocks, 1 float4/thread
    quant_kernel<<<quant_blocks, 256, 0, stream>>>(x, w, aq, bq, amax, n4);

    dim3 grid(N / BN, M / BM);                   // (32, 32)
    gemm_kernel<<<grid, 256, 0, stream>>>(aq, bq, amax, bias, out);
}

// Round 4
// 135.771 us; speedup vs baseline: 2.6036x; 1.1617x over previous
//
#include <hip/hip_runtime.h>
#include <hip/hip_bf16.h>
#include <stdint.h>

static constexpr int M = 4096, N = 4096, K = 4096;
static constexpr float FP8_MAX = 448.0f;

using f32x16 = __attribute__((ext_vector_type(16))) float;
using i32x4  = __attribute__((ext_vector_type(4))) int;
using i32x8  = __attribute__((ext_vector_type(8))) int;

// ---------------- ws layout ----------------
static constexpr size_t AQ_OFF   = 0;
static constexpr size_t BQ_OFF   = (size_t)M * K;
static constexpr size_t AMAX_OFF = BQ_OFF + (size_t)N * K;

// ---------------- init ----------------
__global__ void init_amax_kernel(float* amax) {
    amax[0] = 0.0f;
    amax[1] = 0.0f;
}

// ---------------- amax reduction ----------------
__global__ __launch_bounds__(256) void amax_kernel(const float* __restrict__ x,
                                                   const float* __restrict__ w,
                                                   float* __restrict__ amax,
                                                   int n4_per_tensor,
                                                   int blocks_per_tensor) {
    const int tensor = blockIdx.x / blocks_per_tensor;
    const int blk    = blockIdx.x % blocks_per_tensor;
    const float4* src = (const float4*)(tensor == 0 ? x : w);

    float m = 0.0f;
    for (int i = blk * blockDim.x + threadIdx.x; i < n4_per_tensor;
         i += blocks_per_tensor * blockDim.x) {
        float4 v = src[i];
        m = fmaxf(m, fmaxf(fmaxf(fabsf(v.x), fabsf(v.y)),
                           fmaxf(fabsf(v.z), fabsf(v.w))));
    }
    #pragma unroll
    for (int off = 32; off >= 1; off >>= 1)
        m = fmaxf(m, __shfl_xor(m, off, 64));

    __shared__ float sm[4];
    const int lane = threadIdx.x & 63, wid = threadIdx.x >> 6;
    if (lane == 0) sm[wid] = m;
    __syncthreads();
    if (threadIdx.x == 0) {
        m = fmaxf(fmaxf(sm[0], sm[1]), fmaxf(sm[2], sm[3]));
        atomicMax((unsigned int*)&amax[tensor], __float_as_uint(m));
    }
}

// ---------------- quantize to fp8 e4m3fn ----------------
__global__ __launch_bounds__(256) void quant_kernel(const float* __restrict__ x,
                                                    const float* __restrict__ w,
                                                    unsigned char* __restrict__ aq,
                                                    unsigned char* __restrict__ bq,
                                                    const float* __restrict__ amax,
                                                    int n4_per_tensor) {
    int gid = blockIdx.x * blockDim.x + threadIdx.x;
    const int tensor = (gid >= n4_per_tensor) ? 1 : 0;
    const int i = tensor ? gid - n4_per_tensor : gid;

    const float inv = fmaxf(amax[tensor], 1e-12f) / FP8_MAX;
    const float4* src = (const float4*)(tensor == 0 ? x : w);
    int* dst = (int*)(tensor == 0 ? aq : bq);

    float4 v = src[i];
    float q0 = v.x / inv, q1 = v.y / inv, q2 = v.z / inv, q3 = v.w / inv;
    int packed = __builtin_amdgcn_cvt_pk_fp8_f32(q0, q1, 0, false);
    packed     = __builtin_amdgcn_cvt_pk_fp8_f32(q2, q3, packed, true);
    dst[i] = packed;
}

// ---------------- fp8 GEMM: 256^2 tile, DEPTH-4 ring, counted vmcnt --------
// C[m][n] = sum_k Aq[m][k]*Bq[n][k];  out = C*scale + bias[n]
// 8 waves (2M x 4N), each owns 128x64 via 4x2 tiles of 32x32; MX-scaled
// mfma 32x32x64 with unit E8M0 scales (math == non-scaled fp8).
//
// Ring schedule per K-tile t (one barrier per tile, loads NEVER drained):
//   s_waitcnt vmcnt(8)   ; tile t's 4 loads landed (in-order completion)
//   s_barrier            ; all waves see tile t; all waves done reading t-1
//   STAGE(t+3) -> slot (t+3)&3  ; slot freed by the barrier above
//   ds_read frags of slot t&3 ; MFMA x8 (setprio 1)
//   s_waitcnt lgkmcnt(0) + sched_barrier(0)  ; reads complete before backedge
static constexpr int BM = 256, BN = 256, BK = 64, DEPTH = 4, NT = K / BK;

__device__ __forceinline__ void gld_lds16(const void* g, void* l) {
    __builtin_amdgcn_global_load_lds(
        (const __attribute__((address_space(1))) void*)g,
        (__attribute__((address_space(3))) void*)l, 16, 0, 0);
}

__global__ __launch_bounds__(512, 2) void gemm_kernel(const unsigned char* __restrict__ Aq,
                                                      const unsigned char* __restrict__ Bq,
                                                      const float* __restrict__ amax,
                                                      const float* __restrict__ bias,
                                                      float* __restrict__ out) {
    // [depth][A/B][256 rows x 64 B], chunk-XOR swizzled within each 64 B row
    __shared__ unsigned char lds[DEPTH][2][BM * BK];   // 128 KiB

    const int tid  = threadIdx.x;
    const int lane = tid & 63;
    const int w    = tid >> 6;            // 0..7
    const int wr   = w >> 2, wc = w & 3;  // 2M x 4N waves, 128x64 each

    // XCD-aware swizzle (grid 256 = 32/XCD, bijective since 256 % 8 == 0)
    const int bid = blockIdx.x;
    const int swz = (bid & 7) * 32 + (bid >> 3);
    const int brow = (swz >> 4) * BM;
    const int bcol = (swz & 15) * BN;

    const float sx = fmaxf(amax[0], 1e-12f) / FP8_MAX;
    const float sw = fmaxf(amax[1], 1e-12f) / FP8_MAX;
    const float scale = sx * sw;

    // ---- staging addresses (pre-swizzled global chunk, linear LDS dest) ----
    // wave w covers rows w*16..w*16+15 (call 0) and +128 (call 1); 4 chunks/row
    const int r4    = lane >> 2;
    const int row0  = w * 16 + r4;                       // (row0>>1)&3 == (r4>>1)&3 pattern
    const int chk   = ((lane & 3) ^ ((row0 >> 1) & 3)) * 16;  // +128 rows: same swizzle
    const unsigned char* Abase = Aq + (size_t)brow * K;
    const unsigned char* Bbase = Bq + (size_t)bcol * K;

    // ---- fragment read offsets (32x32x64: row=lane&31, k=(lane>>5)*32+[0..32)) ----
    const int frow = lane & 31;
    const int swzr = (frow >> 1) & 3;       // tile bases are multiples of 32 -> invariant
    const int c0   = (lane >> 5) * 2;
    const int off0 = ((c0 ^ swzr) << 4);
    const int off1 = (((c0 + 1) ^ swzr) << 4);

    f32x16 acc[4][2] = {};

#define STAGE(t, d)                                                              \
    do {                                                                         \
        const int _k0 = (t) * BK;                                                \
        gld_lds16(Abase + (size_t)row0 * K + _k0 + chk,         &lds[d][0][w * 1024]);        \
        gld_lds16(Abase + (size_t)(row0 + 128) * K + _k0 + chk, &lds[d][0][8192 + w * 1024]); \
        gld_lds16(Bbase + (size_t)row0 * K + _k0 + chk,         &lds[d][1][w * 1024]);        \
        gld_lds16(Bbase + (size_t)(row0 + 128) * K + _k0 + chk, &lds[d][1][8192 + w * 1024]); \
    } while (0)

    // prologue: tiles 0,1,2 -> slots 0,1,2
    STAGE(0, 0);
    STAGE(1, 1);
    STAGE(2, 2);

    for (int t = 0; t < NT; ++t) {
        asm volatile("s_waitcnt vmcnt(8)" ::: "memory");   // tile t landed
        __builtin_amdgcn_s_barrier();                      // all waves: t visible, t-1 free

        const int tn = (t + 3 < NT) ? t + 3 : NT - 1;      // clamped tail keeps counts uniform
        STAGE(tn, (t + 3) & 3);

        const int d = t & 3;
        const unsigned char* Ab = &lds[d][0][0];
        const unsigned char* Bb = &lds[d][1][0];

        i32x8 aF[4], bF[2];
        #pragma unroll
        for (int mt = 0; mt < 4; ++mt) {
            const unsigned char* p = Ab + (wr * 128 + mt * 32 + frow) * BK;
            i32x4 lo = *(const i32x4*)(p + off0);
            i32x4 hi = *(const i32x4*)(p + off1);
            aF[mt] = __builtin_shufflevector(lo, hi, 0, 1, 2, 3, 4, 5, 6, 7);
        }
        #pragma unroll
        for (int nt2 = 0; nt2 < 2; ++nt2) {
            const unsigned char* p = Bb + (wc * 64 + nt2 * 32 + frow) * BK;
            i32x4 lo = *(const i32x4*)(p + off0);
            i32x4 hi = *(const i32x4*)(p + off1);
            bF[nt2] = __builtin_shufflevector(lo, hi, 0, 1, 2, 3, 4, 5, 6, 7);
        }

        __builtin_amdgcn_s_setprio(1);
        #pragma unroll
        for (int mt = 0; mt < 4; ++mt)
            #pragma unroll
            for (int nt2 = 0; nt2 < 2; ++nt2)
                acc[mt][nt2] = __builtin_amdgcn_mfma_scale_f32_32x32x64_f8f6f4(
                    aF[mt], bF[nt2], acc[mt][nt2],
                    0, 0, 0, 0x7F, 0, 0x7F);
        __builtin_amdgcn_s_setprio(0);

        // all this wave's ds_reads of slot d complete before it can pass the
        // next barrier (slot d is restaged one iteration later) — rule #18
        asm volatile("s_waitcnt lgkmcnt(0)" ::: "memory");
        __builtin_amdgcn_sched_barrier(0);
    }
#undef STAGE

    // epilogue.  32x32 C/D: col=lane&31, row=(reg&3)+8*(reg>>2)+4*(lane>>5)
    #pragma unroll
    for (int mt = 0; mt < 4; ++mt) {
        const int rbase = brow + wr * 128 + mt * 32 + 4 * (lane >> 5);
        #pragma unroll
        for (int nt2 = 0; nt2 < 2; ++nt2) {
            const int col = bcol + wc * 64 + nt2 * 32 + (lane & 31);
            const float b = bias[col];
            #pragma unroll
            for (int reg = 0; reg < 16; ++reg) {
                const int row = rbase + (reg & 3) + 8 * (reg >> 2);
                out[(size_t)row * N + col] = acc[mt][nt2][reg] * scale + b;
            }
        }
    }
}

extern "C" void kernel_launch(void* const* d_in, const int* in_sizes, int n_in,
                              void* d_out, int out_size, void* d_ws, size_t ws_size,
                              hipStream_t stream) {
    const float* x    = (const float*)d_in[0];   // [4,1024,4096] f32 -> [4096][4096]
    const float* w    = (const float*)d_in[1];   // [4096][4096] f32
    const float* bias = (const float*)d_in[2];   // [4096] f32
    float* out = (float*)d_out;

    unsigned char* aq = (unsigned char*)d_ws + AQ_OFF;
    unsigned char* bq = (unsigned char*)d_ws + BQ_OFF;
    float* amax = (float*)((unsigned char*)d_ws + AMAX_OFF);

    const int n4 = (M * K) / 4;

    init_amax_kernel<<<1, 1, 0, stream>>>(amax);

    const int blocks_per_tensor = 512;
    amax_kernel<<<2 * blocks_per_tensor, 256, 0, stream>>>(x, w, amax, n4, blocks_per_tensor);

    const int quant_blocks = (2 * n4) / 256;
    quant_kernel<<<quant_blocks, 256, 0, stream>>>(x, w, aq, bq, amax, n4);

    gemm_kernel<<<256, 512, 0, stream>>>(aq, bq, amax, bias, out);
}